// Round 13
// baseline (265.082 us; speedup 1.0000x reference)
//
#include <hip/hip_runtime.h>
#include <hip/hip_bf16.h>

#define D 256
#define N0C 100000
#define N1C 20000
#define N2C 4000
#define BCAP 64
#define OVFCAP 4096

typedef short s16x8 __attribute__((ext_vector_type(8)));
typedef float f32x4 __attribute__((ext_vector_type(4)));

typedef __attribute__((address_space(3))) void lds_v;
typedef __attribute__((address_space(1))) void glb_v;

__device__ __forceinline__ short f2bf(float f) {
  __hip_bfloat16 b = __float2bfloat16(f);   // RNE hardware cvt
  union { __hip_bfloat16 h; short s; } u;
  u.h = b;
  return u.s;
}
__device__ __forceinline__ float bf2f(short s) {
  return __uint_as_float(((unsigned)(unsigned short)s) << 16);
}

// ---- weight -> fragment-major packed bf16 (+ zero bucket counters).
__global__ __launch_bounds__(256) void wtransp_k(
    const float* __restrict__ W0, const float* __restrict__ W1,
    const float* __restrict__ W2, const float* __restrict__ W3,
    const float* __restrict__ W4, const float* __restrict__ W5,
    short* __restrict__ T0, short* __restrict__ T1, short* __restrict__ T2,
    short* __restrict__ T3, short* __restrict__ T4, short* __restrict__ T5,
    int* __restrict__ ctrs, int nctr)
{
  int flat = (blockIdx.y * gridDim.x + blockIdx.x) * 256 + threadIdx.x;
  if (flat < nctr) ctrs[flat] = 0;

  const float* Ws[6] = {W0, W1, W2, W3, W4, W5};
  short* Ts[6] = {T0, T1, T2, T3, T4, T5};
  int g = blockIdx.y;
  int c = blockIdx.x * 256 + threadIdx.x;  // 0..8191
  int lane = c & 63, kc = (c >> 6) & 7, g16 = c >> 9;
  int col = g16 * 16 + (lane & 15);
  int kbase = kc * 32 + (lane >> 4) * 8;
  const float* W = Ws[g];
  s16x8 o;
#pragma unroll
  for (int j = 0; j < 8; ++j) o[j] = f2bf(W[(size_t)(kbase + j) * D + col]);
  *(s16x8*)(Ts[g] + (size_t)c * 8) = o;
}

// ---- direct-bucket edge scatter
__global__ __launch_bounds__(256) void scat_direct_k(
    const int* __restrict__ src0, const int* __restrict__ dst0,
    const float* __restrict__ w0, int E0, int* __restrict__ cur0,
    int2* __restrict__ rec0, int* __restrict__ ovfc0, int4* __restrict__ ovf0,
    const int* __restrict__ src1, const int* __restrict__ dst1,
    const float* __restrict__ w1, int E1, int* __restrict__ cur1,
    int2* __restrict__ rec1, int* __restrict__ ovfc1, int4* __restrict__ ovf1)
{
  int i = blockIdx.x * 256 + threadIdx.x;
  if (i < E0) {
    int d = dst0[i];
    int p = atomicAdd(&cur0[d], 1);
    if (p < BCAP) rec0[d * BCAP + p] = make_int2(src0[i], __float_as_int(w0[i]));
    else {
      int q = atomicAdd(ovfc0, 1);
      if (q < OVFCAP) ovf0[q] = make_int4(d, src0[i], __float_as_int(w0[i]), 0);
    }
  } else if (i < E0 + E1) {
    int j = i - E0;
    int d = dst1[j];
    int p = atomicAdd(&cur1[d], 1);
    if (p < BCAP) rec1[d * BCAP + p] = make_int2(src1[j], __float_as_int(w1[j]));
    else {
      int q = atomicAdd(ovfc1, 1);
      if (q < OVFCAP) ovf1[q] = make_int4(d, src1[j], __float_as_int(w1[j]), 0);
    }
  }
}

// ---- standalone per-dst gather max (graph1 only now)
__global__ __launch_bounds__(256) void seg_max_k(
    const short* __restrict__ h, const int* __restrict__ cur,
    const int2* __restrict__ rec, const int* __restrict__ ovfc,
    const int4* __restrict__ ovf, short* __restrict__ agg, int ndst)
{
  int dst = blockIdx.x * 4 + (threadIdx.x >> 6);
  if (dst >= ndst) return;
  int lane = threadIdx.x & 63;
  int cnt = cur[dst];
  cnt = cnt < BCAP ? cnt : BCAP;
  const int2* bp = rec + (size_t)dst * BCAP;
  const short* hp = h + (size_t)lane * 4;
  float m[8][4];
#pragma unroll
  for (int j = 0; j < 8; j++)
#pragma unroll
    for (int d2 = 0; d2 < 4; d2++) m[j][d2] = 0.f;
  int i = 0;
  for (; i + 7 < cnt; i += 8) {
    int2 r[8];
    short4 hv[8];
#pragma unroll
    for (int j = 0; j < 8; ++j) r[j] = bp[i + j];
#pragma unroll
    for (int j = 0; j < 8; ++j) hv[j] = *(const short4*)(hp + (size_t)r[j].x * D);
#pragma unroll
    for (int j = 0; j < 8; ++j) {
      float w = __int_as_float(r[j].y);
      m[j][0] = fmaxf(m[j][0], bf2f(hv[j].x) * w);
      m[j][1] = fmaxf(m[j][1], bf2f(hv[j].y) * w);
      m[j][2] = fmaxf(m[j][2], bf2f(hv[j].z) * w);
      m[j][3] = fmaxf(m[j][3], bf2f(hv[j].w) * w);
    }
  }
  for (; i < cnt; ++i) {
    int2 r0 = bp[i];
    short4 h0 = *(const short4*)(hp + (size_t)r0.x * D);
    float w0 = __int_as_float(r0.y);
    m[0][0] = fmaxf(m[0][0], bf2f(h0.x) * w0); m[0][1] = fmaxf(m[0][1], bf2f(h0.y) * w0);
    m[0][2] = fmaxf(m[0][2], bf2f(h0.z) * w0); m[0][3] = fmaxf(m[0][3], bf2f(h0.w) * w0);
  }
  int novf = *ovfc;
  novf = novf < OVFCAP ? novf : OVFCAP;
  for (int k = 0; k < novf; ++k) {
    int4 e = ovf[k];
    if (e.x == dst) {
      short4 h0 = *(const short4*)(hp + (size_t)e.y * D);
      float w0 = __int_as_float(e.z);
      m[0][0] = fmaxf(m[0][0], bf2f(h0.x) * w0); m[0][1] = fmaxf(m[0][1], bf2f(h0.y) * w0);
      m[0][2] = fmaxf(m[0][2], bf2f(h0.z) * w0); m[0][3] = fmaxf(m[0][3], bf2f(h0.w) * w0);
    }
  }
#pragma unroll
  for (int j = 1; j < 8; ++j)
#pragma unroll
    for (int d2 = 0; d2 < 4; d2++) m[0][d2] = fmaxf(m[0][d2], m[j][d2]);
  short4 o;
  o.x = f2bf(m[0][0]); o.y = f2bf(m[0][1]);
  o.z = f2bf(m[0][2]); o.w = f2bf(m[0][3]);
  *(short4*)(agg + (size_t)dst * D + lane * 4) = o;
}

// ---- GEMM1: h1 = relu(X @ Wp1 + bp1) -> bf16.  Persistent double-buffered
// pipeline: 32-row tiles (8 x 4KB fp32 DMA chunks each), 2 x 32KB LDS bufs,
// (256,2). Per iter: STAGE(t+G, buf^1) -> vmcnt(8) (next tile's DMAs stay
// in flight) -> barrier -> compute buf -> barrier. breg[4][8] = 128 VGPR:
// needs the 256-VGPR budget of 2 blocks/CU (more blocks/CU spills: r8/r9/r11).
__device__ __forceinline__ void stage1_tile(const float* __restrict__ X,
                                            float* smem, int t, int buf,
                                            int tid, int M) {
#pragma unroll
  for (int it = 0; it < 8; ++it) {
    int L = it * 4096 + tid * 16;             // byte offset in 32KB tile
    int row = L >> 10;                        // 1024B per fp32 row
    int colb = (L & 1023) ^ ((row & 7) << 4); // inverse swizzle on source
    int grow = t * 32 + row;
    grow = grow < M ? grow : M - 1;
    const char* gp = (const char*)X + (size_t)grow * 1024 + colb;
    char* lp = (char*)smem + buf * 32768 + L;
    __builtin_amdgcn_global_load_lds((const glb_v*)gp, (lds_v*)lp, 16, 0, 0);
  }
}

__global__ __launch_bounds__(256, 2) void gemm1_k(
    const float* __restrict__ X, const short* __restrict__ Bp,
    const float* __restrict__ bias, short* __restrict__ out,
    int M, int T, int G)
{
  __shared__ float smem[2 * 32 * 256];   // 2 x 32KB fp32 tiles
  const int tid = threadIdx.x;
  const int wave = tid >> 6, lane = tid & 63;
  const int lr = lane & 15, kg = lane >> 4;

  stage1_tile(X, smem, blockIdx.x, 0, tid, M);
  __builtin_amdgcn_sched_barrier(0);

  // B panel + bias resident for the whole block (issued after first STAGE)
  s16x8 breg[4][8];
#pragma unroll
  for (int u = 0; u < 4; ++u)
#pragma unroll
    for (int kc = 0; kc < 8; ++kc) {
      int g16 = wave * 4 + u;
      breg[u][kc] = *(const s16x8*)(Bp + ((size_t)((g16 * 8 + kc) * 64 + lane)) * 8);
    }
  float bv[4];
#pragma unroll
  for (int u = 0; u < 4; ++u) bv[u] = bias[wave * 64 + u * 16 + lr];

  int bufc = 0;
  for (int t = blockIdx.x; t < T; t += G) {
    int tn = t + G;
    if (tn < T) {
      stage1_tile(X, smem, tn, bufc ^ 1, tid, M);
      __builtin_amdgcn_sched_barrier(0);
      // oldest: tile t's 8 DMAs (+ breg on first iter); tn's 8 stay in flight
      asm volatile("s_waitcnt vmcnt(8)" ::: "memory");
    } else {
      asm volatile("s_waitcnt vmcnt(0)" ::: "memory");
    }
    __builtin_amdgcn_s_barrier();
    __builtin_amdgcn_sched_barrier(0);

    const char* sb = (const char*)smem + bufc * 32768;
    f32x4 acc[2][4];
#pragma unroll
    for (int t2 = 0; t2 < 2; t2++)
#pragma unroll
      for (int u = 0; u < 4; u++) acc[t2][u] = (f32x4)(0.0f);

#pragma unroll
    for (int kc = 0; kc < 8; ++kc) {
      s16x8 a[2];
#pragma unroll
      for (int t2 = 0; t2 < 2; ++t2) {
        int row = t2 * 16 + lr;
        int base = (row << 10) + kc * 128 + kg * 32;  // byte addr of 8 fp32
        int swz = (row & 7) << 4;
        f32x4 lo = *(const f32x4*)(sb + ((base) ^ swz));
        f32x4 hi = *(const f32x4*)(sb + ((base + 16) ^ swz));
        a[t2][0] = f2bf(lo[0]); a[t2][1] = f2bf(lo[1]);
        a[t2][2] = f2bf(lo[2]); a[t2][3] = f2bf(lo[3]);
        a[t2][4] = f2bf(hi[0]); a[t2][5] = f2bf(hi[1]);
        a[t2][6] = f2bf(hi[2]); a[t2][7] = f2bf(hi[3]);
      }
#pragma unroll
      for (int t2 = 0; t2 < 2; ++t2)
#pragma unroll
        for (int u = 0; u < 4; ++u)
          acc[t2][u] = __builtin_amdgcn_mfma_f32_16x16x32_bf16(a[t2], breg[u][kc], acc[t2][u], 0, 0, 0);
    }

    // epilogue: D layout col=lane&15, row=(lane>>4)*4+i
    int m_base = t * 32;
#pragma unroll
    for (int t2 = 0; t2 < 2; ++t2) {
      if (m_base + t2 * 16 < M) {
        int grow0 = m_base + t2 * 16 + kg * 4;
#pragma unroll
        for (int u = 0; u < 4; ++u) {
          int col = wave * 64 + u * 16 + lr;
#pragma unroll
          for (int i = 0; i < 4; ++i) {
            float v = acc[t2][u][i] + bv[u];
            v = v > 0.0f ? v : 0.0f;
            out[(size_t)(grow0 + i) * D + col] = f2bf(v);
          }
        }
      }
    }
    __builtin_amdgcn_s_barrier();   // all reads of buf done before it's re-staged
    __builtin_amdgcn_sched_barrier(0);
    bufc ^= 1;
  }
}

// ---- generic GEMM (bf16 A via DMA), used for gemm4
template<int F32OUT>
__global__ __launch_bounds__(256, 2) void gemm2s_k(
    const short* __restrict__ A1, const short* __restrict__ B1p,
    const short* __restrict__ A2, const short* __restrict__ B2p,
    const float* __restrict__ bias, void* __restrict__ outp, int M)
{
  __shared__ short smem[2 * 64 * 256];
  const int tid = threadIdx.x;
  const int wave = tid >> 6, lane = tid & 63;
  const int lr = lane & 15, kg = lane >> 4;
  const int m_base = blockIdx.x * 64;

  const short* As[2] = {A1, A2};
  const short* Bs[2] = {B1p, B2p};

#pragma unroll
  for (int s = 0; s < 2; ++s) {
#pragma unroll
    for (int it = 0; it < 8; ++it) {
      int L = it * 4096 + tid * 16;
      int row = L >> 9;
      int colb = (L & 511) ^ ((row & 7) << 4);
      int grow = m_base + row;
      grow = grow < M ? grow : M - 1;
      const char* gp = (const char*)As[s] + (size_t)grow * 512 + colb;
      char* lp = (char*)smem + s * 32768 + L;
      __builtin_amdgcn_global_load_lds((const glb_v*)gp, (lds_v*)lp, 16, 0, 0);
    }
  }
  __builtin_amdgcn_sched_barrier(0);

  f32x4 acc[4][4];
#pragma unroll
  for (int t = 0; t < 4; t++)
#pragma unroll
    for (int u = 0; u < 4; u++) acc[t][u] = (f32x4)(0.0f);

#pragma unroll
  for (int s = 0; s < 2; ++s) {
    s16x8 breg[4][8];
#pragma unroll
    for (int u = 0; u < 4; ++u)
#pragma unroll
      for (int kc = 0; kc < 8; ++kc) {
        int g16 = wave * 4 + u;
        breg[u][kc] = *(const s16x8*)(Bs[s] + ((size_t)((g16 * 8 + kc) * 64 + lane)) * 8);
      }
    if (s == 0) {
      asm volatile("s_waitcnt vmcnt(32)" ::: "memory");
      __builtin_amdgcn_s_barrier();
      __builtin_amdgcn_sched_barrier(0);
    }
#pragma unroll
    for (int kc = 0; kc < 8; ++kc) {
      s16x8 a[4];
#pragma unroll
      for (int t = 0; t < 4; ++t) {
        int row = t * 16 + lr;
        int base = (row << 9) + kc * 64 + kg * 16;
        int off = s * 32768 + (base ^ ((row & 7) << 4));
        a[t] = *(const s16x8*)((const char*)smem + off);
      }
#pragma unroll
      for (int t = 0; t < 4; ++t)
#pragma unroll
        for (int u = 0; u < 4; ++u)
          acc[t][u] = __builtin_amdgcn_mfma_f32_16x16x32_bf16(a[t], breg[u][kc], acc[t][u], 0, 0, 0);
    }
  }

#pragma unroll
  for (int t = 0; t < 4; ++t) {
    int grow0 = m_base + t * 16 + kg * 4;
    if (m_base + t * 16 < M) {
#pragma unroll
      for (int u = 0; u < 4; ++u) {
        int col = wave * 64 + u * 16 + lr;
        float bvv = bias[col];
#pragma unroll
        for (int i = 0; i < 4; ++i) {
          float v = acc[t][u][i] + bvv;
          v = v > 0.0f ? v : 0.0f;
          size_t idx = (size_t)(grow0 + i) * D + col;
          if (F32OUT) ((float*)outp)[idx] = v;
          else        ((short*)outp)[idx] = f2bf(v);
        }
      }
    }
  }
}

// ---- FUSED: inline seg-max gather (graph0) + layer-1 dst GEMM + layer-2 pre:
//   agg1_tile = segment_max over CSR buckets (gathered straight into LDS)
//   l1o = relu( X @ Ws1 + agg1 @ Wn1 + b1 )   [write only rows < LROWS]
//   h2  = relu( l1o @ Wp2 + bp2 )
// The 256MB h1-gather overlaps the X fp32 DMA. LDS 96KB -> (256,1).
__global__ __launch_bounds__(256, 1) void gemm23_k(
    const float* __restrict__ X, const short* __restrict__ Bs1,
    const short* __restrict__ Bn1, const short* __restrict__ Bp2,
    const float* __restrict__ b1, const float* __restrict__ bp2,
    const short* __restrict__ h1, const int* __restrict__ cur,
    const int2* __restrict__ rec, const int* __restrict__ ovfc,
    const int4* __restrict__ ovf,
    short* __restrict__ l1o, short* __restrict__ h2, int M, int LROWS)
{
  __shared__ float smemf[24576];   // 96KB: X fp32 [0,64K), agg1 bf16 [64K,96K)
  char* smem = (char*)smemf;
  const int tid = threadIdx.x;
  const int wave = tid >> 6, lane = tid & 63;
  const int lr = lane & 15, kg = lane >> 4;
  const int m_base = blockIdx.x * 64;

  // DMA X fp32 tile: 16 chunks x 4KB (oldest in vmcnt FIFO)
#pragma unroll
  for (int it = 0; it < 16; ++it) {
    int L = it * 4096 + tid * 16;
    int row = L >> 10;
    int colb = (L & 1023) ^ ((row & 7) << 4);
    int grow = m_base + row;
    grow = grow < M ? grow : M - 1;
    const char* gp = (const char*)X + (size_t)grow * 1024 + colb;
    char* lp = smem + L;
    __builtin_amdgcn_global_load_lds((const glb_v*)gp, (lds_v*)lp, 16, 0, 0);
  }
  __builtin_amdgcn_sched_barrier(0);

  // ---- inline seg-max gather: wave w computes dsts m_base+16w..+16w+15,
  // writing bf16 short4 into the swizzled agg1 LDS region (overlaps X DMA).
  {
    const short* hp = h1 + (size_t)lane * 4;
    int novf = *ovfc;
    novf = novf < OVFCAP ? novf : OVFCAP;
#pragma unroll 1
    for (int j = 0; j < 16; ++j) {
      int r = wave * 16 + j;            // block-local row
      int dst = m_base + r;
      dst = dst < M ? dst : M - 1;      // clamp (duplicate last; rows unused)
      int cnt = cur[dst];
      cnt = cnt < BCAP ? cnt : BCAP;
      const int2* bp = rec + (size_t)dst * BCAP;
      float m[8][4];
#pragma unroll
      for (int q = 0; q < 8; q++)
#pragma unroll
        for (int d2 = 0; d2 < 4; d2++) m[q][d2] = 0.f;
      int i = 0;
      for (; i + 7 < cnt; i += 8) {
        int2 rr[8];
        short4 hv[8];
#pragma unroll
        for (int q = 0; q < 8; ++q) rr[q] = bp[i + q];
#pragma unroll
        for (int q = 0; q < 8; ++q) hv[q] = *(const short4*)(hp + (size_t)rr[q].x * D);
#pragma unroll
        for (int q = 0; q < 8; ++q) {
          float w = __int_as_float(rr[q].y);
          m[q][0] = fmaxf(m[q][0], bf2f(hv[q].x) * w);
          m[q][1] = fmaxf(m[q][1], bf2f(hv[q].y) * w);
          m[q][2] = fmaxf(m[q][2], bf2f(hv[q].z) * w);
          m[q][3] = fmaxf(m[q][3], bf2f(hv[q].w) * w);
        }
      }
      for (; i < cnt; ++i) {
        int2 r0 = bp[i];
        short4 h0 = *(const short4*)(hp + (size_t)r0.x * D);
        float w0 = __int_as_float(r0.y);
        m[0][0] = fmaxf(m[0][0], bf2f(h0.x) * w0); m[0][1] = fmaxf(m[0][1], bf2f(h0.y) * w0);
        m[0][2] = fmaxf(m[0][2], bf2f(h0.z) * w0); m[0][3] = fmaxf(m[0][3], bf2f(h0.w) * w0);
      }
      for (int k = 0; k < novf; ++k) {
        int4 e = ovf[k];
        if (e.x == dst) {
          short4 h0 = *(const short4*)(hp + (size_t)e.y * D);
          float w0 = __int_as_float(e.z);
          m[0][0] = fmaxf(m[0][0], bf2f(h0.x) * w0); m[0][1] = fmaxf(m[0][1], bf2f(h0.y) * w0);
          m[0][2] = fmaxf(m[0][2], bf2f(h0.z) * w0); m[0][3] = fmaxf(m[0][3], bf2f(h0.w) * w0);
        }
      }
#pragma unroll
      for (int q = 1; q < 8; ++q)
#pragma unroll
        for (int d2 = 0; d2 < 4; d2++) m[0][d2] = fmaxf(m[0][d2], m[q][d2]);
      short4 o;
      o.x = f2bf(m[0][0]); o.y = f2bf(m[0][1]);
      o.z = f2bf(m[0][2]); o.w = f2bf(m[0][3]);
      // swizzled LDS write matching the s=1 read layout (row r, cols lane*4..+3)
      int ba = 65536 + (((r << 9) + lane * 8) ^ ((r & 7) << 4));
      *(short4*)(smem + ba) = o;
    }
  }

  // B panel for s=0 (issued after DMAs + gather loads)
  s16x8 breg[4][8];
#pragma unroll
  for (int u = 0; u < 4; ++u)
#pragma unroll
    for (int kc = 0; kc < 8; ++kc) {
      int g16 = wave * 4 + u;
      breg[u][kc] = *(const s16x8*)(Bs1 + ((size_t)((g16 * 8 + kc) * 64 + lane)) * 8);
    }
  // 16 X-DMAs are the oldest vmem ops; gather loads already consumed.
  // Drain DMAs (<=32 leaves breg in flight) + gather ds_writes (lgkmcnt).
  asm volatile("s_waitcnt vmcnt(32) lgkmcnt(0)" ::: "memory");
  __builtin_amdgcn_s_barrier();
  __builtin_amdgcn_sched_barrier(0);

  f32x4 acc[4][4];
#pragma unroll
  for (int t = 0; t < 4; t++)
#pragma unroll
    for (int u = 0; u < 4; u++) acc[t][u] = (f32x4)(0.0f);

  // s=0: X (fp32 in LDS, cvt at read)
#pragma unroll
  for (int kc = 0; kc < 8; ++kc) {
    s16x8 a[4];
#pragma unroll
    for (int t = 0; t < 4; ++t) {
      int row = t * 16 + lr;
      int base = (row << 10) + kc * 128 + kg * 32;
      int swz = (row & 7) << 4;
      f32x4 lo = *(const f32x4*)(smem + ((base) ^ swz));
      f32x4 hi = *(const f32x4*)(smem + ((base + 16) ^ swz));
      a[t][0] = f2bf(lo[0]); a[t][1] = f2bf(lo[1]);
      a[t][2] = f2bf(lo[2]); a[t][3] = f2bf(lo[3]);
      a[t][4] = f2bf(hi[0]); a[t][5] = f2bf(hi[1]);
      a[t][6] = f2bf(hi[2]); a[t][7] = f2bf(hi[3]);
    }
#pragma unroll
    for (int t = 0; t < 4; ++t)
#pragma unroll
      for (int u = 0; u < 4; ++u)
        acc[t][u] = __builtin_amdgcn_mfma_f32_16x16x32_bf16(a[t], breg[u][kc], acc[t][u], 0, 0, 0);
  }

  // s=1: agg1 (bf16 in LDS, written by the gather)
#pragma unroll
  for (int u = 0; u < 4; ++u)
#pragma unroll
    for (int kc = 0; kc < 8; ++kc) {
      int g16 = wave * 4 + u;
      breg[u][kc] = *(const s16x8*)(Bn1 + ((size_t)((g16 * 8 + kc) * 64 + lane)) * 8);
    }
#pragma unroll
  for (int kc = 0; kc < 8; ++kc) {
    s16x8 a[4];
#pragma unroll
    for (int t = 0; t < 4; ++t) {
      int row = t * 16 + lr;
      int base = (row << 9) + kc * 64 + kg * 16;
      int off = 65536 + (base ^ ((row & 7) << 4));
      a[t] = *(const s16x8*)(smem + off);
    }
#pragma unroll
    for (int t = 0; t < 4; ++t)
#pragma unroll
      for (int u = 0; u < 4; ++u)
        acc[t][u] = __builtin_amdgcn_mfma_f32_16x16x32_bf16(a[t], breg[u][kc], acc[t][u], 0, 0, 0);
  }

  // all waves done reading smem -> safe to reuse X region for l1o tile
  __builtin_amdgcn_s_barrier();
  __builtin_amdgcn_sched_barrier(0);

  // Wp2 panel loads (in flight across epilogue-1)
  s16x8 breg2[4][8];
#pragma unroll
  for (int u = 0; u < 4; ++u)
#pragma unroll
    for (int kc = 0; kc < 8; ++kc) {
      int g16 = wave * 4 + u;
      breg2[u][kc] = *(const s16x8*)(Bp2 + ((size_t)((g16 * 8 + kc) * 64 + lane)) * 8);
    }

  // epilogue-1: l1o = relu(acc+b1); global write (rows<LROWS) + LDS write
#pragma unroll
  for (int t = 0; t < 4; ++t)
#pragma unroll
    for (int u = 0; u < 4; ++u) {
      int col = wave * 64 + u * 16 + lr;
      float bvv = b1[col];
#pragma unroll
      for (int i = 0; i < 4; ++i) {
        int r = t * 16 + kg * 4 + i;   // block-local row
        float v = acc[t][u][i] + bvv;
        v = v > 0.0f ? v : 0.0f;
        short sv = f2bf(v);
        int grow = m_base + r;
        if (grow < LROWS) l1o[(size_t)grow * D + col] = sv;
        int ba = ((r << 9) + 2 * col) ^ ((r & 7) << 4);
        *(short*)(smem + ba) = sv;
      }
    }
  asm volatile("s_waitcnt lgkmcnt(0)" ::: "memory");
  __builtin_amdgcn_s_barrier();
  __builtin_amdgcn_sched_barrier(0);

  // stage-2: h2 = relu(l1o @ Wp2 + bp2)
  f32x4 acc2[4][4];
#pragma unroll
  for (int t = 0; t < 4; t++)
#pragma unroll
    for (int u = 0; u < 4; u++) acc2[t][u] = (f32x4)(0.0f);
#pragma unroll
  for (int kc = 0; kc < 8; ++kc) {
    s16x8 a[4];
#pragma unroll
    for (int t = 0; t < 4; ++t) {
      int row = t * 16 + lr;
      int base = (row << 9) + kc * 64 + kg * 16;
      int off = base ^ ((row & 7) << 4);
      a[t] = *(const s16x8*)(smem + off);
    }
#pragma unroll
    for (int t = 0; t < 4; ++t)
#pragma unroll
      for (int u = 0; u < 4; ++u)
        acc2[t][u] = __builtin_amdgcn_mfma_f32_16x16x32_bf16(a[t], breg2[u][kc], acc2[t][u], 0, 0, 0);
  }

#pragma unroll
  for (int t = 0; t < 4; ++t) {
    int grow0 = m_base + t * 16 + kg * 4;
    if (m_base + t * 16 < M) {
#pragma unroll
      for (int u = 0; u < 4; ++u) {
        int col = wave * 64 + u * 16 + lr;
        float bvv = bp2[col];
#pragma unroll
        for (int i = 0; i < 4; ++i) {
          float v = acc2[t][u][i] + bvv;
          v = v > 0.0f ? v : 0.0f;
          h2[(size_t)(grow0 + i) * D + col] = f2bf(v);
        }
      }
    }
  }
}

extern "C" void kernel_launch(void* const* d_in, const int* in_sizes, int n_in,
                              void* d_out, int out_size, void* d_ws, size_t ws_size,
                              hipStream_t stream)
{
  const float* x    = (const float*)d_in[0];
  const int*   src0 = (const int*)d_in[1];
  const int*   dst0 = (const int*)d_in[2];
  const float* w0   = (const float*)d_in[3];
  const int*   src1 = (const int*)d_in[4];
  const int*   dst1 = (const int*)d_in[5];
  const float* w1   = (const float*)d_in[6];
  const float* Wp1  = (const float*)d_in[7];
  const float* bp1  = (const float*)d_in[8];
  const float* Ws1  = (const float*)d_in[9];
  const float* Wn1  = (const float*)d_in[10];
  const float* b1   = (const float*)d_in[11];
  const float* Wp2  = (const float*)d_in[12];
  const float* bp2  = (const float*)d_in[13];
  const float* Ws2  = (const float*)d_in[14];
  const float* Wn2  = (const float*)d_in[15];
  const float* b2   = (const float*)d_in[16];

  const int E0 = in_sizes[1], E1 = in_sizes[4];
  const int NCTR = N1C + N2C + 2;   // cur0, cur1, ovfc0, ovfc1

  char* ws = (char*)d_ws;
  size_t off = 0;
  auto alloc = [&](size_t bytes) {
    void* p = ws + off;
    off += (bytes + 255) & ~(size_t)255;
    return p;
  };
  short* wp1t = (short*)alloc((size_t)D * D * 2);
  short* ws1t = (short*)alloc((size_t)D * D * 2);
  short* wn1t = (short*)alloc((size_t)D * D * 2);
  short* wp2t = (short*)alloc((size_t)D * D * 2);
  short* ws2t = (short*)alloc((size_t)D * D * 2);
  short* wn2t = (short*)alloc((size_t)D * D * 2);
  short* h1   = (short*)alloc((size_t)N0C * D * 2);
  short* h2   = (short*)alloc((size_t)N1C * D * 2);
  short* l1o  = (short*)alloc((size_t)N2C * D * 2);   // only first 4000 rows needed
  short* agg2 = (short*)alloc((size_t)N2C * D * 2);
  int*   ctrs = (int*)alloc((size_t)NCTR * 4);
  int*   cur0 = ctrs;
  int*   cur1 = ctrs + N1C;
  int*   ovfc0 = ctrs + N1C + N2C;
  int*   ovfc1 = ctrs + N1C + N2C + 1;
  int2*  rec0 = (int2*)alloc((size_t)N1C * BCAP * 8);
  int2*  rec1 = (int2*)alloc((size_t)N2C * BCAP * 8);
  int4*  ovf0 = (int4*)alloc((size_t)OVFCAP * 16);
  int4*  ovf1 = (int4*)alloc((size_t)OVFCAP * 16);

  wtransp_k<<<dim3(32, 6), 256, 0, stream>>>(Wp1, Ws1, Wn1, Wp2, Ws2, Wn2,
                                             wp1t, ws1t, wn1t, wp2t, ws2t, wn2t,
                                             ctrs, NCTR);

  int eb = (E0 + E1 + 255) / 256;
  scat_direct_k<<<eb, 256, 0, stream>>>(src0, dst0, w0, E0, cur0, rec0, ovfc0, ovf0,
                                        src1, dst1, w1, E1, cur1, rec1, ovfc1, ovf1);

  // h1 = relu(x @ Wp1 + bp1) -> bf16   (persistent double-buffered pipeline)
  const int T1 = (N0C + 31) / 32;   // 3125 tiles (exact)
  gemm1_k<<<512, 256, 0, stream>>>(x, wp1t, bp1, h1, N0C, T1, 512);
  // FUSED: agg1-gather + l1o = relu(x@Ws1 + agg1@Wn1 + b1) [rows<4000]
  //        + h2 = relu(l1o @ Wp2 + bp2)
  gemm23_k<<<(N1C + 63) / 64, 256, 0, stream>>>(
      x, ws1t, wn1t, wp2t, b1, bp2,
      h1, cur0, rec0, ovfc0, ovf0, l1o, h2, N1C, N2C);
  // agg2 = segment_max(h2[src1]*w1, dst1) -> bf16
  seg_max_k<<<(N2C + 3) / 4, 256, 0, stream>>>(h2, cur1, rec1, ovfc1, ovf1, agg2, N2C);
  // out = relu(l1o[:N2] @ Ws2 + agg2 @ Wn2 + b2) -> fp32
  gemm2s_k<1><<<(N2C + 63) / 64, 256, 0, stream>>>(
      l1o, ws2t, agg2, wn2t, b2, d_out, N2C);
}

// Round 14
// 162.929 us; speedup vs baseline: 1.6270x; 1.6270x over previous
//
#include <hip/hip_runtime.h>
#include <hip/hip_bf16.h>

#define D 256
#define N0C 100000
#define N1C 20000
#define N2C 4000
#define BCAP 64
#define OVFCAP 4096

typedef short s16x8 __attribute__((ext_vector_type(8)));
typedef float f32x4 __attribute__((ext_vector_type(4)));

typedef __attribute__((address_space(3))) void lds_v;
typedef __attribute__((address_space(1))) void glb_v;

__device__ __forceinline__ short f2bf(float f) {
  __hip_bfloat16 b = __float2bfloat16(f);   // RNE hardware cvt
  union { __hip_bfloat16 h; short s; } u;
  u.h = b;
  return u.s;
}
__device__ __forceinline__ float bf2f(short s) {
  return __uint_as_float(((unsigned)(unsigned short)s) << 16);
}

// ---- weight -> fragment-major packed bf16 (+ zero bucket counters).
__global__ __launch_bounds__(256) void wtransp_k(
    const float* __restrict__ W0, const float* __restrict__ W1,
    const float* __restrict__ W2, const float* __restrict__ W3,
    const float* __restrict__ W4, const float* __restrict__ W5,
    short* __restrict__ T0, short* __restrict__ T1, short* __restrict__ T2,
    short* __restrict__ T3, short* __restrict__ T4, short* __restrict__ T5,
    int* __restrict__ ctrs, int nctr)
{
  int flat = (blockIdx.y * gridDim.x + blockIdx.x) * 256 + threadIdx.x;
  if (flat < nctr) ctrs[flat] = 0;

  const float* Ws[6] = {W0, W1, W2, W3, W4, W5};
  short* Ts[6] = {T0, T1, T2, T3, T4, T5};
  int g = blockIdx.y;
  int c = blockIdx.x * 256 + threadIdx.x;  // 0..8191
  int lane = c & 63, kc = (c >> 6) & 7, g16 = c >> 9;
  int col = g16 * 16 + (lane & 15);
  int kbase = kc * 32 + (lane >> 4) * 8;
  const float* W = Ws[g];
  s16x8 o;
#pragma unroll
  for (int j = 0; j < 8; ++j) o[j] = f2bf(W[(size_t)(kbase + j) * D + col]);
  *(s16x8*)(Ts[g] + (size_t)c * 8) = o;
}

// ---- direct-bucket edge scatter
__global__ __launch_bounds__(256) void scat_direct_k(
    const int* __restrict__ src0, const int* __restrict__ dst0,
    const float* __restrict__ w0, int E0, int* __restrict__ cur0,
    int2* __restrict__ rec0, int* __restrict__ ovfc0, int4* __restrict__ ovf0,
    const int* __restrict__ src1, const int* __restrict__ dst1,
    const float* __restrict__ w1, int E1, int* __restrict__ cur1,
    int2* __restrict__ rec1, int* __restrict__ ovfc1, int4* __restrict__ ovf1)
{
  int i = blockIdx.x * 256 + threadIdx.x;
  if (i < E0) {
    int d = dst0[i];
    int p = atomicAdd(&cur0[d], 1);
    if (p < BCAP) rec0[d * BCAP + p] = make_int2(src0[i], __float_as_int(w0[i]));
    else {
      int q = atomicAdd(ovfc0, 1);
      if (q < OVFCAP) ovf0[q] = make_int4(d, src0[i], __float_as_int(w0[i]), 0);
    }
  } else if (i < E0 + E1) {
    int j = i - E0;
    int d = dst1[j];
    int p = atomicAdd(&cur1[d], 1);
    if (p < BCAP) rec1[d * BCAP + p] = make_int2(src1[j], __float_as_int(w1[j]));
    else {
      int q = atomicAdd(ovfc1, 1);
      if (q < OVFCAP) ovf1[q] = make_int4(d, src1[j], __float_as_int(w1[j]), 0);
    }
  }
}

// ---- per-dst gather max: one wave per dst, 64 lanes x 4 dims, 8-edge unroll.
// High TLP (5000 blocks for graph0) is essential: this is a latency-bound
// random gather -- fusing it into a 313-block GEMM regressed 6x (r13).
__global__ __launch_bounds__(256) void seg_max_k(
    const short* __restrict__ h, const int* __restrict__ cur,
    const int2* __restrict__ rec, const int* __restrict__ ovfc,
    const int4* __restrict__ ovf, short* __restrict__ agg, int ndst)
{
  int dst = blockIdx.x * 4 + (threadIdx.x >> 6);
  if (dst >= ndst) return;
  int lane = threadIdx.x & 63;
  int cnt = cur[dst];
  cnt = cnt < BCAP ? cnt : BCAP;
  const int2* bp = rec + (size_t)dst * BCAP;
  const short* hp = h + (size_t)lane * 4;
  float m[8][4];
#pragma unroll
  for (int j = 0; j < 8; j++)
#pragma unroll
    for (int d2 = 0; d2 < 4; d2++) m[j][d2] = 0.f;
  int i = 0;
  for (; i + 7 < cnt; i += 8) {
    int2 r[8];
    short4 hv[8];
#pragma unroll
    for (int j = 0; j < 8; ++j) r[j] = bp[i + j];
#pragma unroll
    for (int j = 0; j < 8; ++j) hv[j] = *(const short4*)(hp + (size_t)r[j].x * D);
#pragma unroll
    for (int j = 0; j < 8; ++j) {
      float w = __int_as_float(r[j].y);
      m[j][0] = fmaxf(m[j][0], bf2f(hv[j].x) * w);
      m[j][1] = fmaxf(m[j][1], bf2f(hv[j].y) * w);
      m[j][2] = fmaxf(m[j][2], bf2f(hv[j].z) * w);
      m[j][3] = fmaxf(m[j][3], bf2f(hv[j].w) * w);
    }
  }
  for (; i < cnt; ++i) {
    int2 r0 = bp[i];
    short4 h0 = *(const short4*)(hp + (size_t)r0.x * D);
    float w0 = __int_as_float(r0.y);
    m[0][0] = fmaxf(m[0][0], bf2f(h0.x) * w0); m[0][1] = fmaxf(m[0][1], bf2f(h0.y) * w0);
    m[0][2] = fmaxf(m[0][2], bf2f(h0.z) * w0); m[0][3] = fmaxf(m[0][3], bf2f(h0.w) * w0);
  }
  int novf = *ovfc;
  novf = novf < OVFCAP ? novf : OVFCAP;
  for (int k = 0; k < novf; ++k) {
    int4 e = ovf[k];
    if (e.x == dst) {
      short4 h0 = *(const short4*)(hp + (size_t)e.y * D);
      float w0 = __int_as_float(e.z);
      m[0][0] = fmaxf(m[0][0], bf2f(h0.x) * w0); m[0][1] = fmaxf(m[0][1], bf2f(h0.y) * w0);
      m[0][2] = fmaxf(m[0][2], bf2f(h0.z) * w0); m[0][3] = fmaxf(m[0][3], bf2f(h0.w) * w0);
    }
  }
#pragma unroll
  for (int j = 1; j < 8; ++j)
#pragma unroll
    for (int d2 = 0; d2 < 4; d2++) m[0][d2] = fmaxf(m[0][d2], m[j][d2]);
  short4 o;
  o.x = f2bf(m[0][0]); o.y = f2bf(m[0][1]);
  o.z = f2bf(m[0][2]); o.w = f2bf(m[0][3]);
  *(short4*)(agg + (size_t)dst * D + lane * 4) = o;
}

// ---- GEMM1: h1 = relu(X @ Wp1 + bp1) -> bf16.  fp32 A-tile via DMA.
// 64-row x 256-col block (64KB LDS), (256,2) -- NOTE: breg[4][8] alone is
// 128 VGPRs; this structure needs the full 256-VGPR budget of 2 blocks/CU.
// Declaring more blocks/CU spills to scratch (r8, r9, r11 all regressed).
__global__ __launch_bounds__(256, 2) void gemm1_k(
    const float* __restrict__ X, const short* __restrict__ Bp,
    const float* __restrict__ bias, short* __restrict__ out, int M)
{
  __shared__ float smem[64 * 256];   // 64KB fp32 tile
  const int tid = threadIdx.x;
  const int wave = tid >> 6, lane = tid & 63;
  const int lr = lane & 15, kg = lane >> 4;
  const int m_base = blockIdx.x * 64;

  // DMA fp32 tile: 16 chunks x 4KB (issued first -> oldest in vmcnt FIFO)
#pragma unroll
  for (int it = 0; it < 16; ++it) {
    int L = it * 4096 + tid * 16;             // byte offset in 64KB tile
    int row = L >> 10;                        // 1024B per fp32 row
    int colb = (L & 1023) ^ ((row & 7) << 4); // inverse swizzle on source
    int grow = m_base + row;
    grow = grow < M ? grow : M - 1;
    const char* gp = (const char*)X + (size_t)grow * 1024 + colb;
    char* lp = (char*)smem + L;
    __builtin_amdgcn_global_load_lds((const glb_v*)gp, (lds_v*)lp, 16, 0, 0);
  }
  __builtin_amdgcn_sched_barrier(0);

  // B panel + bias resident (issued after DMAs)
  s16x8 breg[4][8];
#pragma unroll
  for (int u = 0; u < 4; ++u)
#pragma unroll
    for (int kc = 0; kc < 8; ++kc) {
      int g16 = wave * 4 + u;
      breg[u][kc] = *(const s16x8*)(Bp + ((size_t)((g16 * 8 + kc) * 64 + lane)) * 8);
    }
  float bv[4];
#pragma unroll
  for (int u = 0; u < 4; ++u) bv[u] = bias[wave * 64 + u * 16 + lr];

  // 16 DMAs oldest; done when <=32 outstanding (B loads stay in flight)
  asm volatile("s_waitcnt vmcnt(32)" ::: "memory");
  __builtin_amdgcn_s_barrier();
  __builtin_amdgcn_sched_barrier(0);

  f32x4 acc[4][4];
#pragma unroll
  for (int t = 0; t < 4; t++)
#pragma unroll
    for (int u = 0; u < 4; u++) acc[t][u] = (f32x4)(0.0f);

#pragma unroll
  for (int kc = 0; kc < 8; ++kc) {
    s16x8 a[4];
#pragma unroll
    for (int t = 0; t < 4; ++t) {
      int row = t * 16 + lr;
      int base = (row << 10) + kc * 128 + kg * 32;  // byte addr of 8 fp32
      int swz = (row & 7) << 4;
      f32x4 lo = *(const f32x4*)((const char*)smem + ((base) ^ swz));
      f32x4 hi = *(const f32x4*)((const char*)smem + ((base + 16) ^ swz));
      a[t][0] = f2bf(lo[0]); a[t][1] = f2bf(lo[1]);
      a[t][2] = f2bf(lo[2]); a[t][3] = f2bf(lo[3]);
      a[t][4] = f2bf(hi[0]); a[t][5] = f2bf(hi[1]);
      a[t][6] = f2bf(hi[2]); a[t][7] = f2bf(hi[3]);
    }
#pragma unroll
    for (int t = 0; t < 4; ++t)
#pragma unroll
      for (int u = 0; u < 4; ++u)
        acc[t][u] = __builtin_amdgcn_mfma_f32_16x16x32_bf16(a[t], breg[u][kc], acc[t][u], 0, 0, 0);
  }

  // epilogue: D layout col=lane&15, row=(lane>>4)*4+i
#pragma unroll
  for (int t = 0; t < 4; ++t) {
    if (m_base + t * 16 < M) {
      int grow0 = m_base + t * 16 + kg * 4;
#pragma unroll
      for (int u = 0; u < 4; ++u) {
        int col = wave * 64 + u * 16 + lr;
#pragma unroll
        for (int i = 0; i < 4; ++i) {
          float v = acc[t][u][i] + bv[u];
          v = v > 0.0f ? v : 0.0f;
          out[(size_t)(grow0 + i) * D + col] = f2bf(v);
        }
      }
    }
  }
}

// ---- generic GEMM (bf16 A via DMA), used for gemm4
template<int F32OUT>
__global__ __launch_bounds__(256, 2) void gemm2s_k(
    const short* __restrict__ A1, const short* __restrict__ B1p,
    const short* __restrict__ A2, const short* __restrict__ B2p,
    const float* __restrict__ bias, void* __restrict__ outp, int M)
{
  __shared__ short smem[2 * 64 * 256];
  const int tid = threadIdx.x;
  const int wave = tid >> 6, lane = tid & 63;
  const int lr = lane & 15, kg = lane >> 4;
  const int m_base = blockIdx.x * 64;

  const short* As[2] = {A1, A2};
  const short* Bs[2] = {B1p, B2p};

#pragma unroll
  for (int s = 0; s < 2; ++s) {
#pragma unroll
    for (int it = 0; it < 8; ++it) {
      int L = it * 4096 + tid * 16;
      int row = L >> 9;
      int colb = (L & 511) ^ ((row & 7) << 4);
      int grow = m_base + row;
      grow = grow < M ? grow : M - 1;
      const char* gp = (const char*)As[s] + (size_t)grow * 512 + colb;
      char* lp = (char*)smem + s * 32768 + L;
      __builtin_amdgcn_global_load_lds((const glb_v*)gp, (lds_v*)lp, 16, 0, 0);
    }
  }
  __builtin_amdgcn_sched_barrier(0);

  f32x4 acc[4][4];
#pragma unroll
  for (int t = 0; t < 4; t++)
#pragma unroll
    for (int u = 0; u < 4; u++) acc[t][u] = (f32x4)(0.0f);

#pragma unroll
  for (int s = 0; s < 2; ++s) {
    s16x8 breg[4][8];
#pragma unroll
    for (int u = 0; u < 4; ++u)
#pragma unroll
      for (int kc = 0; kc < 8; ++kc) {
        int g16 = wave * 4 + u;
        breg[u][kc] = *(const s16x8*)(Bs[s] + ((size_t)((g16 * 8 + kc) * 64 + lane)) * 8);
      }
    if (s == 0) {
      asm volatile("s_waitcnt vmcnt(32)" ::: "memory");
      __builtin_amdgcn_s_barrier();
      __builtin_amdgcn_sched_barrier(0);
    }
#pragma unroll
    for (int kc = 0; kc < 8; ++kc) {
      s16x8 a[4];
#pragma unroll
      for (int t = 0; t < 4; ++t) {
        int row = t * 16 + lr;
        int base = (row << 9) + kc * 64 + kg * 16;
        int off = s * 32768 + (base ^ ((row & 7) << 4));
        a[t] = *(const s16x8*)((const char*)smem + off);
      }
#pragma unroll
      for (int t = 0; t < 4; ++t)
#pragma unroll
        for (int u = 0; u < 4; ++u)
          acc[t][u] = __builtin_amdgcn_mfma_f32_16x16x32_bf16(a[t], breg[u][kc], acc[t][u], 0, 0, 0);
    }
  }

#pragma unroll
  for (int t = 0; t < 4; ++t) {
    int grow0 = m_base + t * 16 + kg * 4;
    if (m_base + t * 16 < M) {
#pragma unroll
      for (int u = 0; u < 4; ++u) {
        int col = wave * 64 + u * 16 + lr;
        float bvv = bias[col];
#pragma unroll
        for (int i = 0; i < 4; ++i) {
          float v = acc[t][u][i] + bvv;
          v = v > 0.0f ? v : 0.0f;
          size_t idx = (size_t)(grow0 + i) * D + col;
          if (F32OUT) ((float*)outp)[idx] = v;
          else        ((short*)outp)[idx] = f2bf(v);
        }
      }
    }
  }
}

// ---- FUSED layer-1 dst GEMM + layer-2 pre GEMM (r7/r10-validated version):
//   l1o = relu( X @ Ws1 + agg1 @ Wn1 + b1 )   [write only rows < LROWS]
//   h2  = relu( l1o @ Wp2 + bp2 )
__global__ __launch_bounds__(256, 2) void gemm23_k(
    const float* __restrict__ X, const short* __restrict__ Bs1,
    const short* __restrict__ A2, const short* __restrict__ Bn1,
    const short* __restrict__ Bp2,
    const float* __restrict__ b1, const float* __restrict__ bp2,
    short* __restrict__ l1o, short* __restrict__ h2, int M, int LROWS)
{
  __shared__ short smem[2 * 64 * 256];
  const int tid = threadIdx.x;
  const int wave = tid >> 6, lane = tid & 63;
  const int lr = lane & 15, kg = lane >> 4;
  const int m_base = blockIdx.x * 64;

  const short* Bs[2] = {Bs1, Bn1};

#pragma unroll
  for (int it = 0; it < 8; ++it) {
    int L = it * 4096 + tid * 16;
    int row = L >> 9;
    int colb = (L & 511) ^ ((row & 7) << 4);
    int grow = m_base + row;
    grow = grow < M ? grow : M - 1;
    const char* gp = (const char*)A2 + (size_t)grow * 512 + colb;
    char* lp = (char*)smem + 32768 + L;
    __builtin_amdgcn_global_load_lds((const glb_v*)gp, (lds_v*)lp, 16, 0, 0);
  }
  __builtin_amdgcn_sched_barrier(0);

  {
    float4 fa[8][2];
#pragma unroll
    for (int it = 0; it < 8; ++it) {
      int L = it * 4096 + tid * 16;
      int row = L >> 9;
      int colel = (L & 511) >> 1;
      int grow = m_base + row;
      grow = grow < M ? grow : M - 1;
      const float* gp = X + (size_t)grow * D + colel;
      fa[it][0] = *(const float4*)gp;
      fa[it][1] = *(const float4*)(gp + 4);
    }
#pragma unroll
    for (int it = 0; it < 8; ++it) {
      int L = it * 4096 + tid * 16;
      int row = L >> 9;
      int Lw = L ^ ((row & 7) << 4);
      s16x8 o;
      o[0] = f2bf(fa[it][0].x); o[1] = f2bf(fa[it][0].y);
      o[2] = f2bf(fa[it][0].z); o[3] = f2bf(fa[it][0].w);
      o[4] = f2bf(fa[it][1].x); o[5] = f2bf(fa[it][1].y);
      o[6] = f2bf(fa[it][1].z); o[7] = f2bf(fa[it][1].w);
      *(s16x8*)((char*)smem + Lw) = o;
    }
    __builtin_amdgcn_sched_barrier(0);
  }

  f32x4 acc[4][4];
#pragma unroll
  for (int t = 0; t < 4; t++)
#pragma unroll
    for (int u = 0; u < 4; u++) acc[t][u] = (f32x4)(0.0f);

#pragma unroll
  for (int s = 0; s < 2; ++s) {
    s16x8 breg[4][8];
#pragma unroll
    for (int u = 0; u < 4; ++u)
#pragma unroll
      for (int kc = 0; kc < 8; ++kc) {
        int g16 = wave * 4 + u;
        breg[u][kc] = *(const s16x8*)(Bs[s] + ((size_t)((g16 * 8 + kc) * 64 + lane)) * 8);
      }
    if (s == 0) {
      __syncthreads();
      __builtin_amdgcn_sched_barrier(0);
    }
#pragma unroll
    for (int kc = 0; kc < 8; ++kc) {
      s16x8 a[4];
#pragma unroll
      for (int t = 0; t < 4; ++t) {
        int row = t * 16 + lr;
        int base = (row << 9) + kc * 64 + kg * 16;
        int off = s * 32768 + (base ^ ((row & 7) << 4));
        a[t] = *(const s16x8*)((const char*)smem + off);
      }
#pragma unroll
      for (int t = 0; t < 4; ++t)
#pragma unroll
        for (int u = 0; u < 4; ++u)
          acc[t][u] = __builtin_amdgcn_mfma_f32_16x16x32_bf16(a[t], breg[u][kc], acc[t][u], 0, 0, 0);
    }
  }

  __builtin_amdgcn_s_barrier();
  __builtin_amdgcn_sched_barrier(0);

  s16x8 breg2[4][8];
#pragma unroll
  for (int u = 0; u < 4; ++u)
#pragma unroll
    for (int kc = 0; kc < 8; ++kc) {
      int g16 = wave * 4 + u;
      breg2[u][kc] = *(const s16x8*)(Bp2 + ((size_t)((g16 * 8 + kc) * 64 + lane)) * 8);
    }

#pragma unroll
  for (int t = 0; t < 4; ++t)
#pragma unroll
    for (int u = 0; u < 4; ++u) {
      int col = wave * 64 + u * 16 + lr;
      float bvv = b1[col];
#pragma unroll
      for (int i = 0; i < 4; ++i) {
        int r = t * 16 + kg * 4 + i;
        float v = acc[t][u][i] + bvv;
        v = v > 0.0f ? v : 0.0f;
        short sv = f2bf(v);
        int grow = m_base + r;
        if (grow < LROWS) l1o[(size_t)grow * D + col] = sv;
        int ba = ((r << 9) + 2 * col) ^ ((r & 7) << 4);
        *(short*)((char*)smem + ba) = sv;
      }
    }
  asm volatile("s_waitcnt lgkmcnt(0)" ::: "memory");
  __builtin_amdgcn_s_barrier();
  __builtin_amdgcn_sched_barrier(0);

  f32x4 acc2[4][4];
#pragma unroll
  for (int t = 0; t < 4; t++)
#pragma unroll
    for (int u = 0; u < 4; u++) acc2[t][u] = (f32x4)(0.0f);
#pragma unroll
  for (int kc = 0; kc < 8; ++kc) {
    s16x8 a[4];
#pragma unroll
    for (int t = 0; t < 4; ++t) {
      int row = t * 16 + lr;
      int base = (row << 9) + kc * 64 + kg * 16;
      int off = base ^ ((row & 7) << 4);
      a[t] = *(const s16x8*)((const char*)smem + off);
    }
#pragma unroll
    for (int t = 0; t < 4; ++t)
#pragma unroll
      for (int u = 0; u < 4; ++u)
        acc2[t][u] = __builtin_amdgcn_mfma_f32_16x16x32_bf16(a[t], breg2[u][kc], acc2[t][u], 0, 0, 0);
  }

#pragma unroll
  for (int t = 0; t < 4; ++t) {
    int grow0 = m_base + t * 16 + kg * 4;
    if (m_base + t * 16 < M) {
#pragma unroll
      for (int u = 0; u < 4; ++u) {
        int col = wave * 64 + u * 16 + lr;
        float bvv = bp2[col];
#pragma unroll
        for (int i = 0; i < 4; ++i) {
          float v = acc2[t][u][i] + bvv;
          v = v > 0.0f ? v : 0.0f;
          h2[(size_t)(grow0 + i) * D + col] = f2bf(v);
        }
      }
    }
  }
}

extern "C" void kernel_launch(void* const* d_in, const int* in_sizes, int n_in,
                              void* d_out, int out_size, void* d_ws, size_t ws_size,
                              hipStream_t stream)
{
  const float* x    = (const float*)d_in[0];
  const int*   src0 = (const int*)d_in[1];
  const int*   dst0 = (const int*)d_in[2];
  const float* w0   = (const float*)d_in[3];
  const int*   src1 = (const int*)d_in[4];
  const int*   dst1 = (const int*)d_in[5];
  const float* w1   = (const float*)d_in[6];
  const float* Wp1  = (const float*)d_in[7];
  const float* bp1  = (const float*)d_in[8];
  const float* Ws1  = (const float*)d_in[9];
  const float* Wn1  = (const float*)d_in[10];
  const float* b1   = (const float*)d_in[11];
  const float* Wp2  = (const float*)d_in[12];
  const float* bp2  = (const float*)d_in[13];
  const float* Ws2  = (const float*)d_in[14];
  const float* Wn2  = (const float*)d_in[15];
  const float* b2   = (const float*)d_in[16];

  const int E0 = in_sizes[1], E1 = in_sizes[4];
  const int NCTR = N1C + N2C + 2;   // cur0, cur1, ovfc0, ovfc1

  char* ws = (char*)d_ws;
  size_t off = 0;
  auto alloc = [&](size_t bytes) {
    void* p = ws + off;
    off += (bytes + 255) & ~(size_t)255;
    return p;
  };
  short* wp1t = (short*)alloc((size_t)D * D * 2);
  short* ws1t = (short*)alloc((size_t)D * D * 2);
  short* wn1t = (short*)alloc((size_t)D * D * 2);
  short* wp2t = (short*)alloc((size_t)D * D * 2);
  short* ws2t = (short*)alloc((size_t)D * D * 2);
  short* wn2t = (short*)alloc((size_t)D * D * 2);
  short* h1   = (short*)alloc((size_t)N0C * D * 2);
  short* h2   = (short*)alloc((size_t)N1C * D * 2);
  short* l1o  = (short*)alloc((size_t)N2C * D * 2);   // only first 4000 rows needed
  short* agg1 = (short*)alloc((size_t)N1C * D * 2);
  short* agg2 = (short*)alloc((size_t)N2C * D * 2);
  int*   ctrs = (int*)alloc((size_t)NCTR * 4);
  int*   cur0 = ctrs;
  int*   cur1 = ctrs + N1C;
  int*   ovfc0 = ctrs + N1C + N2C;
  int*   ovfc1 = ctrs + N1C + N2C + 1;
  int2*  rec0 = (int2*)alloc((size_t)N1C * BCAP * 8);
  int2*  rec1 = (int2*)alloc((size_t)N2C * BCAP * 8);
  int4*  ovf0 = (int4*)alloc((size_t)OVFCAP * 16);
  int4*  ovf1 = (int4*)alloc((size_t)OVFCAP * 16);

  wtransp_k<<<dim3(32, 6), 256, 0, stream>>>(Wp1, Ws1, Wn1, Wp2, Ws2, Wn2,
                                             wp1t, ws1t, wn1t, wp2t, ws2t, wn2t,
                                             ctrs, NCTR);

  int eb = (E0 + E1 + 255) / 256;
  scat_direct_k<<<eb, 256, 0, stream>>>(src0, dst0, w0, E0, cur0, rec0, ovfc0, ovf0,
                                        src1, dst1, w1, E1, cur1, rec1, ovfc1, ovf1);

  // h1 = relu(x @ Wp1 + bp1) -> bf16   (r10-validated fp32-DMA 64-row tiles)
  gemm1_k<<<(N0C + 63) / 64, 256, 0, stream>>>(x, wp1t, bp1, h1, N0C);
  // agg1 = segment_max(h1[src0]*w0, dst0) -> bf16
  seg_max_k<<<(N1C + 3) / 4, 256, 0, stream>>>(h1, cur0, rec0, ovfc0, ovf0, agg1, N1C);
  // FUSED: l1o = relu(x@Ws1 + agg1@Wn1 + b1) [rows<4000]; h2 = relu(l1o@Wp2 + bp2)
  gemm23_k<<<(N1C + 63) / 64, 256, 0, stream>>>(
      x, ws1t, agg1, wn1t, wp2t, b1, bp2, l1o, h2, N1C, N2C);
  // agg2 = segment_max(h2[src1]*w1, dst1) -> bf16
  seg_max_k<<<(N2C + 3) / 4, 256, 0, stream>>>(h2, cur1, rec1, ovfc1, ovf1, agg2, N2C);
  // out = relu(l1o[:N2] @ Ws2 + agg2 @ Wn2 + b2) -> fp32
  gemm2s_k<1><<<(N2C + 63) / 64, 256, 0, stream>>>(
      l1o, ws2t, agg2, wn2t, b2, d_out, N2C);
}

// Round 15
// 156.579 us; speedup vs baseline: 1.6930x; 1.0405x over previous
//
#include <hip/hip_runtime.h>
#include <hip/hip_bf16.h>

#define D 256
#define N0C 100000
#define N1C 20000
#define N2C 4000
#define BCAP 64
#define OVFCAP 4096

typedef short s16x8 __attribute__((ext_vector_type(8)));
typedef float f32x4 __attribute__((ext_vector_type(4)));

typedef __attribute__((address_space(3))) void lds_v;
typedef __attribute__((address_space(1))) void glb_v;

__device__ __forceinline__ short f2bf(float f) {
  __hip_bfloat16 b = __float2bfloat16(f);   // RNE hardware cvt
  union { __hip_bfloat16 h; short s; } u;
  u.h = b;
  return u.s;
}
__device__ __forceinline__ float bf2f(short s) {
  return __uint_as_float(((unsigned)(unsigned short)s) << 16);
}

// ---- weight -> fragment-major packed bf16 (+ zero bucket counters).
__global__ __launch_bounds__(256) void wtransp_k(
    const float* __restrict__ W0, const float* __restrict__ W1,
    const float* __restrict__ W2, const float* __restrict__ W3,
    const float* __restrict__ W4, const float* __restrict__ W5,
    short* __restrict__ T0, short* __restrict__ T1, short* __restrict__ T2,
    short* __restrict__ T3, short* __restrict__ T4, short* __restrict__ T5,
    int* __restrict__ ctrs, int nctr)
{
  int flat = (blockIdx.y * gridDim.x + blockIdx.x) * 256 + threadIdx.x;
  if (flat < nctr) ctrs[flat] = 0;

  const float* Ws[6] = {W0, W1, W2, W3, W4, W5};
  short* Ts[6] = {T0, T1, T2, T3, T4, T5};
  int g = blockIdx.y;
  int c = blockIdx.x * 256 + threadIdx.x;  // 0..8191
  int lane = c & 63, kc = (c >> 6) & 7, g16 = c >> 9;
  int col = g16 * 16 + (lane & 15);
  int kbase = kc * 32 + (lane >> 4) * 8;
  const float* W = Ws[g];
  s16x8 o;
#pragma unroll
  for (int j = 0; j < 8; ++j) o[j] = f2bf(W[(size_t)(kbase + j) * D + col]);
  *(s16x8*)(Ts[g] + (size_t)c * 8) = o;
}

// ---- direct-bucket edge scatter
__global__ __launch_bounds__(256) void scat_direct_k(
    const int* __restrict__ src0, const int* __restrict__ dst0,
    const float* __restrict__ w0, int E0, int* __restrict__ cur0,
    int2* __restrict__ rec0, int* __restrict__ ovfc0, int4* __restrict__ ovf0,
    const int* __restrict__ src1, const int* __restrict__ dst1,
    const float* __restrict__ w1, int E1, int* __restrict__ cur1,
    int2* __restrict__ rec1, int* __restrict__ ovfc1, int4* __restrict__ ovf1)
{
  int i = blockIdx.x * 256 + threadIdx.x;
  if (i < E0) {
    int d = dst0[i];
    int p = atomicAdd(&cur0[d], 1);
    if (p < BCAP) rec0[d * BCAP + p] = make_int2(src0[i], __float_as_int(w0[i]));
    else {
      int q = atomicAdd(ovfc0, 1);
      if (q < OVFCAP) ovf0[q] = make_int4(d, src0[i], __float_as_int(w0[i]), 0);
    }
  } else if (i < E0 + E1) {
    int j = i - E0;
    int d = dst1[j];
    int p = atomicAdd(&cur1[d], 1);
    if (p < BCAP) rec1[d * BCAP + p] = make_int2(src1[j], __float_as_int(w1[j]));
    else {
      int q = atomicAdd(ovfc1, 1);
      if (q < OVFCAP) ovf1[q] = make_int4(d, src1[j], __float_as_int(w1[j]), 0);
    }
  }
}

// ---- per-dst gather max: one wave per dst, 64 lanes x 4 dims, 8-edge unroll.
// High TLP (5000 blocks for graph0) is essential: this is a latency-bound
// random gather -- fusing it into a 313-block GEMM regressed 6x (r13).
__global__ __launch_bounds__(256) void seg_max_k(
    const short* __restrict__ h, const int* __restrict__ cur,
    const int2* __restrict__ rec, const int* __restrict__ ovfc,
    const int4* __restrict__ ovf, short* __restrict__ agg, int ndst)
{
  int dst = blockIdx.x * 4 + (threadIdx.x >> 6);
  if (dst >= ndst) return;
  int lane = threadIdx.x & 63;
  int cnt = cur[dst];
  cnt = cnt < BCAP ? cnt : BCAP;
  const int2* bp = rec + (size_t)dst * BCAP;
  const short* hp = h + (size_t)lane * 4;
  float m[8][4];
#pragma unroll
  for (int j = 0; j < 8; j++)
#pragma unroll
    for (int d2 = 0; d2 < 4; d2++) m[j][d2] = 0.f;
  int i = 0;
  for (; i + 7 < cnt; i += 8) {
    int2 r[8];
    short4 hv[8];
#pragma unroll
    for (int j = 0; j < 8; ++j) r[j] = bp[i + j];
#pragma unroll
    for (int j = 0; j < 8; ++j) hv[j] = *(const short4*)(hp + (size_t)r[j].x * D);
#pragma unroll
    for (int j = 0; j < 8; ++j) {
      float w = __int_as_float(r[j].y);
      m[j][0] = fmaxf(m[j][0], bf2f(hv[j].x) * w);
      m[j][1] = fmaxf(m[j][1], bf2f(hv[j].y) * w);
      m[j][2] = fmaxf(m[j][2], bf2f(hv[j].z) * w);
      m[j][3] = fmaxf(m[j][3], bf2f(hv[j].w) * w);
    }
  }
  for (; i < cnt; ++i) {
    int2 r0 = bp[i];
    short4 h0 = *(const short4*)(hp + (size_t)r0.x * D);
    float w0 = __int_as_float(r0.y);
    m[0][0] = fmaxf(m[0][0], bf2f(h0.x) * w0); m[0][1] = fmaxf(m[0][1], bf2f(h0.y) * w0);
    m[0][2] = fmaxf(m[0][2], bf2f(h0.z) * w0); m[0][3] = fmaxf(m[0][3], bf2f(h0.w) * w0);
  }
  int novf = *ovfc;
  novf = novf < OVFCAP ? novf : OVFCAP;
  for (int k = 0; k < novf; ++k) {
    int4 e = ovf[k];
    if (e.x == dst) {
      short4 h0 = *(const short4*)(hp + (size_t)e.y * D);
      float w0 = __int_as_float(e.z);
      m[0][0] = fmaxf(m[0][0], bf2f(h0.x) * w0); m[0][1] = fmaxf(m[0][1], bf2f(h0.y) * w0);
      m[0][2] = fmaxf(m[0][2], bf2f(h0.z) * w0); m[0][3] = fmaxf(m[0][3], bf2f(h0.w) * w0);
    }
  }
#pragma unroll
  for (int j = 1; j < 8; ++j)
#pragma unroll
    for (int d2 = 0; d2 < 4; d2++) m[0][d2] = fmaxf(m[0][d2], m[j][d2]);
  short4 o;
  o.x = f2bf(m[0][0]); o.y = f2bf(m[0][1]);
  o.z = f2bf(m[0][2]); o.w = f2bf(m[0][3]);
  *(short4*)(agg + (size_t)dst * D + lane * 4) = o;
}

// ---- GEMM1: h1 = relu(X @ Wp1 + bp1) -> bf16.  Persistent double-buffered
// pipeline (r12/r13-correctness-validated): 32-row tiles (8 x 4KB fp32 DMA
// chunks), 2 x 32KB LDS bufs, (256,2). Per iter: STAGE(t+G, buf^1) ->
// vmcnt(8) (next tile's DMAs stay in flight) -> barrier -> compute buf ->
// barrier. breg[4][8] = 128 VGPR: needs the full 256-VGPR budget of
// 2 blocks/CU (more blocks/CU spills: r8/r9/r11).
__device__ __forceinline__ void stage1_tile(const float* __restrict__ X,
                                            float* smem, int t, int buf,
                                            int tid, int M) {
#pragma unroll
  for (int it = 0; it < 8; ++it) {
    int L = it * 4096 + tid * 16;             // byte offset in 32KB tile
    int row = L >> 10;                        // 1024B per fp32 row
    int colb = (L & 1023) ^ ((row & 7) << 4); // inverse swizzle on source
    int grow = t * 32 + row;
    grow = grow < M ? grow : M - 1;
    const char* gp = (const char*)X + (size_t)grow * 1024 + colb;
    char* lp = (char*)smem + buf * 32768 + L;
    __builtin_amdgcn_global_load_lds((const glb_v*)gp, (lds_v*)lp, 16, 0, 0);
  }
}

__global__ __launch_bounds__(256, 2) void gemm1_k(
    const float* __restrict__ X, const short* __restrict__ Bp,
    const float* __restrict__ bias, short* __restrict__ out,
    int M, int T, int G)
{
  __shared__ float smem[2 * 32 * 256];   // 2 x 32KB fp32 tiles
  const int tid = threadIdx.x;
  const int wave = tid >> 6, lane = tid & 63;
  const int lr = lane & 15, kg = lane >> 4;

  stage1_tile(X, smem, blockIdx.x, 0, tid, M);
  __builtin_amdgcn_sched_barrier(0);

  // B panel + bias resident for the whole block (issued after first STAGE)
  s16x8 breg[4][8];
#pragma unroll
  for (int u = 0; u < 4; ++u)
#pragma unroll
    for (int kc = 0; kc < 8; ++kc) {
      int g16 = wave * 4 + u;
      breg[u][kc] = *(const s16x8*)(Bp + ((size_t)((g16 * 8 + kc) * 64 + lane)) * 8);
    }
  float bv[4];
#pragma unroll
  for (int u = 0; u < 4; ++u) bv[u] = bias[wave * 64 + u * 16 + lr];

  int bufc = 0;
  for (int t = blockIdx.x; t < T; t += G) {
    int tn = t + G;
    if (tn < T) {
      stage1_tile(X, smem, tn, bufc ^ 1, tid, M);
      __builtin_amdgcn_sched_barrier(0);
      // oldest: tile t's 8 DMAs (+ breg/bias on first iter); tn's 8 in flight
      asm volatile("s_waitcnt vmcnt(8)" ::: "memory");
    } else {
      asm volatile("s_waitcnt vmcnt(0)" ::: "memory");
    }
    __builtin_amdgcn_s_barrier();
    __builtin_amdgcn_sched_barrier(0);

    const char* sb = (const char*)smem + bufc * 32768;
    f32x4 acc[2][4];
#pragma unroll
    for (int t2 = 0; t2 < 2; t2++)
#pragma unroll
      for (int u = 0; u < 4; u++) acc[t2][u] = (f32x4)(0.0f);

#pragma unroll
    for (int kc = 0; kc < 8; ++kc) {
      s16x8 a[2];
#pragma unroll
      for (int t2 = 0; t2 < 2; ++t2) {
        int row = t2 * 16 + lr;
        int base = (row << 10) + kc * 128 + kg * 32;  // byte addr of 8 fp32
        int swz = (row & 7) << 4;
        f32x4 lo = *(const f32x4*)(sb + ((base) ^ swz));
        f32x4 hi = *(const f32x4*)(sb + ((base + 16) ^ swz));
        a[t2][0] = f2bf(lo[0]); a[t2][1] = f2bf(lo[1]);
        a[t2][2] = f2bf(lo[2]); a[t2][3] = f2bf(lo[3]);
        a[t2][4] = f2bf(hi[0]); a[t2][5] = f2bf(hi[1]);
        a[t2][6] = f2bf(hi[2]); a[t2][7] = f2bf(hi[3]);
      }
#pragma unroll
      for (int t2 = 0; t2 < 2; ++t2)
#pragma unroll
        for (int u = 0; u < 4; ++u)
          acc[t2][u] = __builtin_amdgcn_mfma_f32_16x16x32_bf16(a[t2], breg[u][kc], acc[t2][u], 0, 0, 0);
    }

    // epilogue: D layout col=lane&15, row=(lane>>4)*4+i
    int m_base = t * 32;
#pragma unroll
    for (int t2 = 0; t2 < 2; ++t2) {
      if (m_base + t2 * 16 < M) {
        int grow0 = m_base + t2 * 16 + kg * 4;
#pragma unroll
        for (int u = 0; u < 4; ++u) {
          int col = wave * 64 + u * 16 + lr;
#pragma unroll
          for (int i = 0; i < 4; ++i) {
            float v = acc[t2][u][i] + bv[u];
            v = v > 0.0f ? v : 0.0f;
            out[(size_t)(grow0 + i) * D + col] = f2bf(v);
          }
        }
      }
    }
    __builtin_amdgcn_s_barrier();   // all reads of buf done before re-stage
    __builtin_amdgcn_sched_barrier(0);
    bufc ^= 1;
  }
}

// ---- generic GEMM (bf16 A via DMA), used for gemm4
template<int F32OUT>
__global__ __launch_bounds__(256, 2) void gemm2s_k(
    const short* __restrict__ A1, const short* __restrict__ B1p,
    const short* __restrict__ A2, const short* __restrict__ B2p,
    const float* __restrict__ bias, void* __restrict__ outp, int M)
{
  __shared__ short smem[2 * 64 * 256];
  const int tid = threadIdx.x;
  const int wave = tid >> 6, lane = tid & 63;
  const int lr = lane & 15, kg = lane >> 4;
  const int m_base = blockIdx.x * 64;

  const short* As[2] = {A1, A2};
  const short* Bs[2] = {B1p, B2p};

#pragma unroll
  for (int s = 0; s < 2; ++s) {
#pragma unroll
    for (int it = 0; it < 8; ++it) {
      int L = it * 4096 + tid * 16;
      int row = L >> 9;
      int colb = (L & 511) ^ ((row & 7) << 4);
      int grow = m_base + row;
      grow = grow < M ? grow : M - 1;
      const char* gp = (const char*)As[s] + (size_t)grow * 512 + colb;
      char* lp = (char*)smem + s * 32768 + L;
      __builtin_amdgcn_global_load_lds((const glb_v*)gp, (lds_v*)lp, 16, 0, 0);
    }
  }
  __builtin_amdgcn_sched_barrier(0);

  f32x4 acc[4][4];
#pragma unroll
  for (int t = 0; t < 4; t++)
#pragma unroll
    for (int u = 0; u < 4; u++) acc[t][u] = (f32x4)(0.0f);

#pragma unroll
  for (int s = 0; s < 2; ++s) {
    s16x8 breg[4][8];
#pragma unroll
    for (int u = 0; u < 4; ++u)
#pragma unroll
      for (int kc = 0; kc < 8; ++kc) {
        int g16 = wave * 4 + u;
        breg[u][kc] = *(const s16x8*)(Bs[s] + ((size_t)((g16 * 8 + kc) * 64 + lane)) * 8);
      }
    if (s == 0) {
      asm volatile("s_waitcnt vmcnt(32)" ::: "memory");
      __builtin_amdgcn_s_barrier();
      __builtin_amdgcn_sched_barrier(0);
    }
#pragma unroll
    for (int kc = 0; kc < 8; ++kc) {
      s16x8 a[4];
#pragma unroll
      for (int t = 0; t < 4; ++t) {
        int row = t * 16 + lr;
        int base = (row << 9) + kc * 64 + kg * 16;
        int off = s * 32768 + (base ^ ((row & 7) << 4));
        a[t] = *(const s16x8*)((const char*)smem + off);
      }
#pragma unroll
      for (int t = 0; t < 4; ++t)
#pragma unroll
        for (int u = 0; u < 4; ++u)
          acc[t][u] = __builtin_amdgcn_mfma_f32_16x16x32_bf16(a[t], breg[u][kc], acc[t][u], 0, 0, 0);
    }
  }

#pragma unroll
  for (int t = 0; t < 4; ++t) {
    int grow0 = m_base + t * 16 + kg * 4;
    if (m_base + t * 16 < M) {
#pragma unroll
      for (int u = 0; u < 4; ++u) {
        int col = wave * 64 + u * 16 + lr;
        float bvv = bias[col];
#pragma unroll
        for (int i = 0; i < 4; ++i) {
          float v = acc[t][u][i] + bvv;
          v = v > 0.0f ? v : 0.0f;
          size_t idx = (size_t)(grow0 + i) * D + col;
          if (F32OUT) ((float*)outp)[idx] = v;
          else        ((short*)outp)[idx] = f2bf(v);
        }
      }
    }
  }
}

// ---- FUSED layer-1 dst GEMM + layer-2 pre GEMM (r7/r10-validated version):
//   l1o = relu( X @ Ws1 + agg1 @ Wn1 + b1 )   [write only rows < LROWS]
//   h2  = relu( l1o @ Wp2 + bp2 )
__global__ __launch_bounds__(256, 2) void gemm23_k(
    const float* __restrict__ X, const short* __restrict__ Bs1,
    const short* __restrict__ A2, const short* __restrict__ Bn1,
    const short* __restrict__ Bp2,
    const float* __restrict__ b1, const float* __restrict__ bp2,
    short* __restrict__ l1o, short* __restrict__ h2, int M, int LROWS)
{
  __shared__ short smem[2 * 64 * 256];
  const int tid = threadIdx.x;
  const int wave = tid >> 6, lane = tid & 63;
  const int lr = lane & 15, kg = lane >> 4;
  const int m_base = blockIdx.x * 64;

  const short* Bs[2] = {Bs1, Bn1};

#pragma unroll
  for (int it = 0; it < 8; ++it) {
    int L = it * 4096 + tid * 16;
    int row = L >> 9;
    int colb = (L & 511) ^ ((row & 7) << 4);
    int grow = m_base + row;
    grow = grow < M ? grow : M - 1;
    const char* gp = (const char*)A2 + (size_t)grow * 512 + colb;
    char* lp = (char*)smem + 32768 + L;
    __builtin_amdgcn_global_load_lds((const glb_v*)gp, (lds_v*)lp, 16, 0, 0);
  }
  __builtin_amdgcn_sched_barrier(0);

  {
    float4 fa[8][2];
#pragma unroll
    for (int it = 0; it < 8; ++it) {
      int L = it * 4096 + tid * 16;
      int row = L >> 9;
      int colel = (L & 511) >> 1;
      int grow = m_base + row;
      grow = grow < M ? grow : M - 1;
      const float* gp = X + (size_t)grow * D + colel;
      fa[it][0] = *(const float4*)gp;
      fa[it][1] = *(const float4*)(gp + 4);
    }
#pragma unroll
    for (int it = 0; it < 8; ++it) {
      int L = it * 4096 + tid * 16;
      int row = L >> 9;
      int Lw = L ^ ((row & 7) << 4);
      s16x8 o;
      o[0] = f2bf(fa[it][0].x); o[1] = f2bf(fa[it][0].y);
      o[2] = f2bf(fa[it][0].z); o[3] = f2bf(fa[it][0].w);
      o[4] = f2bf(fa[it][1].x); o[5] = f2bf(fa[it][1].y);
      o[6] = f2bf(fa[it][1].z); o[7] = f2bf(fa[it][1].w);
      *(s16x8*)((char*)smem + Lw) = o;
    }
    __builtin_amdgcn_sched_barrier(0);
  }

  f32x4 acc[4][4];
#pragma unroll
  for (int t = 0; t < 4; t++)
#pragma unroll
    for (int u = 0; u < 4; u++) acc[t][u] = (f32x4)(0.0f);

#pragma unroll
  for (int s = 0; s < 2; ++s) {
    s16x8 breg[4][8];
#pragma unroll
    for (int u = 0; u < 4; ++u)
#pragma unroll
      for (int kc = 0; kc < 8; ++kc) {
        int g16 = wave * 4 + u;
        breg[u][kc] = *(const s16x8*)(Bs[s] + ((size_t)((g16 * 8 + kc) * 64 + lane)) * 8);
      }
    if (s == 0) {
      __syncthreads();
      __builtin_amdgcn_sched_barrier(0);
    }
#pragma unroll
    for (int kc = 0; kc < 8; ++kc) {
      s16x8 a[4];
#pragma unroll
      for (int t = 0; t < 4; ++t) {
        int row = t * 16 + lr;
        int base = (row << 9) + kc * 64 + kg * 16;
        int off = s * 32768 + (base ^ ((row & 7) << 4));
        a[t] = *(const s16x8*)((const char*)smem + off);
      }
#pragma unroll
      for (int t = 0; t < 4; ++t)
#pragma unroll
        for (int u = 0; u < 4; ++u)
          acc[t][u] = __builtin_amdgcn_mfma_f32_16x16x32_bf16(a[t], breg[u][kc], acc[t][u], 0, 0, 0);
    }
  }

  __builtin_amdgcn_s_barrier();
  __builtin_amdgcn_sched_barrier(0);

  s16x8 breg2[4][8];
#pragma unroll
  for (int u = 0; u < 4; ++u)
#pragma unroll
    for (int kc = 0; kc < 8; ++kc) {
      int g16 = wave * 4 + u;
      breg2[u][kc] = *(const s16x8*)(Bp2 + ((size_t)((g16 * 8 + kc) * 64 + lane)) * 8);
    }

#pragma unroll
  for (int t = 0; t < 4; ++t)
#pragma unroll
    for (int u = 0; u < 4; ++u) {
      int col = wave * 64 + u * 16 + lr;
      float bvv = b1[col];
#pragma unroll
      for (int i = 0; i < 4; ++i) {
        int r = t * 16 + kg * 4 + i;
        float v = acc[t][u][i] + bvv;
        v = v > 0.0f ? v : 0.0f;
        short sv = f2bf(v);
        int grow = m_base + r;
        if (grow < LROWS) l1o[(size_t)grow * D + col] = sv;
        int ba = ((r << 9) + 2 * col) ^ ((r & 7) << 4);
        *(short*)((char*)smem + ba) = sv;
      }
    }
  asm volatile("s_waitcnt lgkmcnt(0)" ::: "memory");
  __builtin_amdgcn_s_barrier();
  __builtin_amdgcn_sched_barrier(0);

  f32x4 acc2[4][4];
#pragma unroll
  for (int t = 0; t < 4; t++)
#pragma unroll
    for (int u = 0; u < 4; u++) acc2[t][u] = (f32x4)(0.0f);
#pragma unroll
  for (int kc = 0; kc < 8; ++kc) {
    s16x8 a[4];
#pragma unroll
    for (int t = 0; t < 4; ++t) {
      int row = t * 16 + lr;
      int base = (row << 9) + kc * 64 + kg * 16;
      int off = base ^ ((row & 7) << 4);
      a[t] = *(const s16x8*)((const char*)smem + off);
    }
#pragma unroll
    for (int t = 0; t < 4; ++t)
#pragma unroll
      for (int u = 0; u < 4; ++u)
        acc2[t][u] = __builtin_amdgcn_mfma_f32_16x16x32_bf16(a[t], breg2[u][kc], acc2[t][u], 0, 0, 0);
  }

#pragma unroll
  for (int t = 0; t < 4; ++t) {
    int grow0 = m_base + t * 16 + kg * 4;
    if (m_base + t * 16 < M) {
#pragma unroll
      for (int u = 0; u < 4; ++u) {
        int col = wave * 64 + u * 16 + lr;
        float bvv = bp2[col];
#pragma unroll
        for (int i = 0; i < 4; ++i) {
          float v = acc2[t][u][i] + bvv;
          v = v > 0.0f ? v : 0.0f;
          h2[(size_t)(grow0 + i) * D + col] = f2bf(v);
        }
      }
    }
  }
}

extern "C" void kernel_launch(void* const* d_in, const int* in_sizes, int n_in,
                              void* d_out, int out_size, void* d_ws, size_t ws_size,
                              hipStream_t stream)
{
  const float* x    = (const float*)d_in[0];
  const int*   src0 = (const int*)d_in[1];
  const int*   dst0 = (const int*)d_in[2];
  const float* w0   = (const float*)d_in[3];
  const int*   src1 = (const int*)d_in[4];
  const int*   dst1 = (const int*)d_in[5];
  const float* w1   = (const float*)d_in[6];
  const float* Wp1  = (const float*)d_in[7];
  const float* bp1  = (const float*)d_in[8];
  const float* Ws1  = (const float*)d_in[9];
  const float* Wn1  = (const float*)d_in[10];
  const float* b1   = (const float*)d_in[11];
  const float* Wp2  = (const float*)d_in[12];
  const float* bp2  = (const float*)d_in[13];
  const float* Ws2  = (const float*)d_in[14];
  const float* Wn2  = (const float*)d_in[15];
  const float* b2   = (const float*)d_in[16];

  const int E0 = in_sizes[1], E1 = in_sizes[4];
  const int NCTR = N1C + N2C + 2;   // cur0, cur1, ovfc0, ovfc1

  char* ws = (char*)d_ws;
  size_t off = 0;
  auto alloc = [&](size_t bytes) {
    void* p = ws + off;
    off += (bytes + 255) & ~(size_t)255;
    return p;
  };
  short* wp1t = (short*)alloc((size_t)D * D * 2);
  short* ws1t = (short*)alloc((size_t)D * D * 2);
  short* wn1t = (short*)alloc((size_t)D * D * 2);
  short* wp2t = (short*)alloc((size_t)D * D * 2);
  short* ws2t = (short*)alloc((size_t)D * D * 2);
  short* wn2t = (short*)alloc((size_t)D * D * 2);
  short* h1   = (short*)alloc((size_t)N0C * D * 2);
  short* h2   = (short*)alloc((size_t)N1C * D * 2);
  short* l1o  = (short*)alloc((size_t)N2C * D * 2);   // only first 4000 rows needed
  short* agg1 = (short*)alloc((size_t)N1C * D * 2);
  short* agg2 = (short*)alloc((size_t)N2C * D * 2);
  int*   ctrs = (int*)alloc((size_t)NCTR * 4);
  int*   cur0 = ctrs;
  int*   cur1 = ctrs + N1C;
  int*   ovfc0 = ctrs + N1C + N2C;
  int*   ovfc1 = ctrs + N1C + N2C + 1;
  int2*  rec0 = (int2*)alloc((size_t)N1C * BCAP * 8);
  int2*  rec1 = (int2*)alloc((size_t)N2C * BCAP * 8);
  int4*  ovf0 = (int4*)alloc((size_t)OVFCAP * 16);
  int4*  ovf1 = (int4*)alloc((size_t)OVFCAP * 16);

  wtransp_k<<<dim3(32, 6), 256, 0, stream>>>(Wp1, Ws1, Wn1, Wp2, Ws2, Wn2,
                                             wp1t, ws1t, wn1t, wp2t, ws2t, wn2t,
                                             ctrs, NCTR);

  int eb = (E0 + E1 + 255) / 256;
  scat_direct_k<<<eb, 256, 0, stream>>>(src0, dst0, w0, E0, cur0, rec0, ovfc0, ovf0,
                                        src1, dst1, w1, E1, cur1, rec1, ovfc1, ovf1);

  // h1 = relu(x @ Wp1 + bp1) -> bf16   (persistent double-buffered pipeline)
  const int T1 = (N0C + 31) / 32;   // 3125 tiles
  gemm1_k<<<512, 256, 0, stream>>>(x, wp1t, bp1, h1, N0C, T1, 512);
  // agg1 = segment_max(h1[src0]*w0, dst0) -> bf16
  seg_max_k<<<(N1C + 3) / 4, 256, 0, stream>>>(h1, cur0, rec0, ovfc0, ovf0, agg1, N1C);
  // FUSED: l1o = relu(x@Ws1 + agg1@Wn1 + b1) [rows<4000]; h2 = relu(l1o@Wp2 + bp2)
  gemm23_k<<<(N1C + 63) / 64, 256, 0, stream>>>(
      x, ws1t, agg1, wn1t, wp2t, b1, bp2, l1o, h2, N1C, N2C);
  // agg2 = segment_max(h2[src1]*w1, dst1) -> bf16
  seg_max_k<<<(N2C + 3) / 4, 256, 0, stream>>>(h2, cur1, rec1, ovfc1, ovf1, agg2, N2C);
  // out = relu(l1o[:N2] @ Ws2 + agg2 @ Wn2 + b2) -> fp32
  gemm2s_k<1><<<(N2C + 63) / 64, 256, 0, stream>>>(
      l1o, ws2t, agg2, wn2t, b2, d_out, N2C);
}